// Round 9
// baseline (37.558 us; speedup 1.0000x reference)
//
#include <hip/hip_runtime.h>
#include <math.h>

#define D 512
#define NROWS 4096
#define BATCH 16
#define CHUNKS 64           // chunks per batch
#define ROWS_PER_CHUNK 64   // NROWS / CHUNKS
#define MAIN_THREADS 256    // 4 waves
#define WAVES 4
#define PASSES 2            // DIAGNOSTIC: 2 identical passes; out = p/l is invariant

// workspace layout (in floats)
#define WS_U    0                      // 512
#define WS_L    512                    // BATCH*CHUNKS = 1024 partial denominators
#define WS_P    (WS_L + BATCH*CHUNKS)  // BATCH*CHUNKS*D partial numerators

typedef float f32x4 __attribute__((ext_vector_type(4)));

// ---------- u[d] = sum_e v[e]*W[e,d]  (c = b.v cancels in softmax; dropped) ----------
__global__ __launch_bounds__(256) void k_u(const float* __restrict__ W,
                                           const float* __restrict__ v,
                                           float* __restrict__ u) {
  int j = blockIdx.x;             // 32 blocks, 16 cols each
  int t = threadIdx.x;            // 256
  int col = t & 15, rc = t >> 4;  // 16 row-chunks of 32 rows
  int d = j * 16 + col;
  float s = 0.f;
#pragma unroll 8
  for (int i = 0; i < 32; ++i) {
    int e = rc * 32 + i;
    s = fmaf(v[e], W[e * D + d], s);
  }
  __shared__ float red[16][17];
  red[rc][col] = s;
  __syncthreads();
  if (rc == 0) {
    float tot = 0.f;
#pragma unroll
    for (int i = 0; i < 16; ++i) tot += red[i][col];
    u[d] = tot;
  }
}

// ---------- main: compaction + chain-free exp(s)-weighted accumulation ----------
__global__ __launch_bounds__(MAIN_THREADS) void k_main(
    const float* __restrict__ x, const int* __restrict__ mask,
    const float* __restrict__ u,
    float* __restrict__ lsum, float* __restrict__ psum) {
  int chunk = blockIdx.x, b = blockIdx.y;
  int t = threadIdx.x;
  int lane = t & 63, w = t >> 6;

  const f32x4* u4 = (const f32x4*)u;
  f32x4 ua = u4[lane];        // d = 4*lane .. 4*lane+3
  f32x4 ub = u4[64 + lane];   // d = 256+4*lane ..

  int base = b * NROWS + chunk * ROWS_PER_CHUNK;

  // ---- compaction: valid-row list (wave 0), then broadcast to registers ----
  __shared__ int s_list[ROWS_PER_CHUNK];
  __shared__ int s_cnt;
  if (w == 0) {
    s_list[lane] = 0;
    int mv = mask[base + lane];                 // one coalesced 256B load
    unsigned long long bal = __ballot(mv == 1);
    int pos = __popcll(bal & ((1ull << lane) - 1ull));
    if (mv == 1) s_list[pos] = lane;
    if (lane == 0) s_cnt = (int)__popcll(bal);
  }
  __syncthreads();
  int cnt = s_cnt;
  int myl = s_list[lane];     // whole list in one register per lane

  const f32x4* xb = (const f32x4*)x + (size_t)base * (D / 4);

  float l = 0.f;
  f32x4 accA = {0.f, 0.f, 0.f, 0.f}, accB = {0.f, 0.f, 0.f, 0.f};
  for (int pass = 0; pass < PASSES; ++pass) {
#pragma unroll 4
    for (int i = w; i < cnt; i += WAVES) {
      int r = __shfl(myl, i);   // row id broadcast, no LDS in address chain
      const f32x4* xp = xb + r * (D / 4);
      f32x4 a = xp[lane];
      f32x4 bb = xp[64 + lane];
      float s = a.x * ua.x + a.y * ua.y + a.z * ua.z + a.w * ua.w
              + bb.x * ub.x + bb.y * ub.y + bb.z * ub.z + bb.w * ub.w;
#pragma unroll
      for (int off = 32; off > 0; off >>= 1) s += __shfl_xor(s, off);
      float wg = __expf(s);
      l += wg;
      accA += a * wg;
      accB += bb * wg;
    }
  }

  // ---- cross-wave reduce + record ----
  __shared__ float pbuf[WAVES][D];
  __shared__ float s_l[WAVES];
  if (lane == 0) s_l[w] = l;
  *(f32x4*)&pbuf[w][4 * lane] = accA;
  *(f32x4*)&pbuf[w][256 + 4 * lane] = accB;
  __syncthreads();

  int rid = b * CHUNKS + chunk;
  if (t == 0) lsum[rid] = s_l[0] + s_l[1] + s_l[2] + s_l[3];
#pragma unroll
  for (int col = t; col < D; col += MAIN_THREADS) {
    float sum = 0.f;
#pragma unroll
    for (int i = 0; i < WAVES; ++i) sum += pbuf[i][col];
    psum[(size_t)rid * D + col] = sum;
  }
}

// ---------- combine chunk partials per batch (float4-vectorized) ----------
__global__ __launch_bounds__(128) void k_combine(const float* __restrict__ lsum,
                                                 const float* __restrict__ psum,
                                                 float* __restrict__ out) {
  int b = blockIdx.x;          // 16
  int t = threadIdx.x;         // 128 threads x 4 cols = 512
  __shared__ float sl[CHUNKS];
  if (t < CHUNKS) sl[t] = lsum[b * CHUNKS + t];
  __syncthreads();
  float ltot = 0.f;
#pragma unroll
  for (int i = 0; i < CHUNKS; ++i) ltot += sl[i];
  f32x4 o = {0.f, 0.f, 0.f, 0.f};
#pragma unroll 8
  for (int i = 0; i < CHUNKS; ++i)
    o += *(const f32x4*)&psum[(size_t)(b * CHUNKS + i) * D + t * 4];
  float inv = 1.0f / ltot;
  *(f32x4*)&out[b * D + t * 4] = o * inv;
}

extern "C" void kernel_launch(void* const* d_in, const int* in_sizes, int n_in,
                              void* d_out, int out_size, void* d_ws, size_t ws_size,
                              hipStream_t stream) {
  const float* x    = (const float*)d_in[0];
  const int*   mask = (const int*)d_in[1];
  const float* W    = (const float*)d_in[2];
  const float* v    = (const float*)d_in[4];
  float* out = (float*)d_out;
  float* ws  = (float*)d_ws;

  float* u    = ws + WS_U;
  float* lsum = ws + WS_L;
  float* psum = ws + WS_P;

  k_u<<<32, 256, 0, stream>>>(W, v, u);
  dim3 g(CHUNKS, BATCH);
  k_main<<<g, MAIN_THREADS, 0, stream>>>(x, mask, u, lsum, psum);
  k_combine<<<BATCH, 128, 0, stream>>>(lsum, psum, out);
}

// Round 10
// 27.778 us; speedup vs baseline: 1.3521x; 1.3521x over previous
//
#include <hip/hip_runtime.h>
#include <math.h>

#define D 512
#define NROWS 4096
#define BATCH 16
#define CHUNKS 64           // chunks per batch
#define ROWS_PER_CHUNK 64   // NROWS / CHUNKS
#define MAIN_THREADS 256    // 4 waves
#define WAVES 4

// workspace layout (in floats)
#define WS_U    0                      // 512
#define WS_L    512                    // BATCH*CHUNKS = 1024 partial denominators
#define WS_P    (WS_L + BATCH*CHUNKS)  // BATCH*CHUNKS*D partial numerators

typedef float f32x4 __attribute__((ext_vector_type(4)));

__device__ __forceinline__ float rowdot(f32x4 a, f32x4 b, f32x4 ua, f32x4 ub) {
  return a.x * ua.x + a.y * ua.y + a.z * ua.z + a.w * ua.w
       + b.x * ub.x + b.y * ub.y + b.z * ub.z + b.w * ub.w;
}

// ---------- u[d] = sum_e v[e]*W[e,d]  (c = b.v cancels in softmax; dropped) ----------
__global__ __launch_bounds__(256) void k_u(const float* __restrict__ W,
                                           const float* __restrict__ v,
                                           float* __restrict__ u) {
  int j = blockIdx.x;             // 32 blocks, 16 cols each
  int t = threadIdx.x;            // 256
  int col = t & 15, rc = t >> 4;  // 16 row-chunks of 32 rows
  int d = j * 16 + col;
  float s = 0.f;
#pragma unroll 8
  for (int i = 0; i < 32; ++i) {
    int e = rc * 32 + i;
    s = fmaf(v[e], W[e * D + d], s);
  }
  __shared__ float red[16][17];
  red[rc][col] = s;
  __syncthreads();
  if (rc == 0) {
    float tot = 0.f;
#pragma unroll
    for (int i = 0; i < 16; ++i) tot += red[i][col];
    u[d] = tot;
  }
}

// ---------- main: compaction + chain-free exp(s)-weighted accumulation ----------
// Grouped-4 rows: 8 loads issued together, 4 butterflies interleaved (ILP on
// the LDS pipe), 4 exps together, register-resident accumulate. No max
// subtraction (scores ~N(0,6^2), far from f32 exp overflow).
__global__ __launch_bounds__(MAIN_THREADS, 4) void k_main(
    const float* __restrict__ x, const int* __restrict__ mask,
    const float* __restrict__ u,
    float* __restrict__ lsum, float* __restrict__ psum) {
  int chunk = blockIdx.x, b = blockIdx.y;
  int t = threadIdx.x;
  int lane = t & 63, w = t >> 6;

  const f32x4* u4 = (const f32x4*)u;
  f32x4 ua = u4[lane];        // d = 4*lane .. 4*lane+3
  f32x4 ub = u4[64 + lane];   // d = 256+4*lane ..

  int base = b * NROWS + chunk * ROWS_PER_CHUNK;

  // ---- compaction: valid-row list (wave 0), then broadcast to registers ----
  __shared__ int s_list[ROWS_PER_CHUNK];
  __shared__ int s_cnt;
  if (w == 0) {
    s_list[lane] = 0;
    int mv = mask[base + lane];                 // one coalesced 256B load
    unsigned long long bal = __ballot(mv == 1);
    int pos = __popcll(bal & ((1ull << lane) - 1ull));
    if (mv == 1) s_list[pos] = lane;
    if (lane == 0) s_cnt = (int)__popcll(bal);
  }
  __syncthreads();
  int cnt = s_cnt;
  int myl = s_list[lane];     // whole list in one register per lane

  const f32x4* xb = (const f32x4*)x + (size_t)base * (D / 4);

  float l = 0.f;
  f32x4 accA = {0.f, 0.f, 0.f, 0.f}, accB = {0.f, 0.f, 0.f, 0.f};

  int i = w;
#pragma unroll 2
  for (; i + 3 * WAVES < cnt; i += 4 * WAVES) {
    int r0 = __shfl(myl, i);
    int r1 = __shfl(myl, i + WAVES);
    int r2 = __shfl(myl, i + 2 * WAVES);
    int r3 = __shfl(myl, i + 3 * WAVES);
    const f32x4* p0 = xb + r0 * (D / 4);
    const f32x4* p1 = xb + r1 * (D / 4);
    const f32x4* p2 = xb + r2 * (D / 4);
    const f32x4* p3 = xb + r3 * (D / 4);
    f32x4 a0 = p0[lane], b0 = p0[64 + lane];   // 8 loads in flight together
    f32x4 a1 = p1[lane], b1 = p1[64 + lane];
    f32x4 a2 = p2[lane], b2 = p2[64 + lane];
    f32x4 a3 = p3[lane], b3 = p3[64 + lane];
    float s0 = rowdot(a0, b0, ua, ub);
    float s1 = rowdot(a1, b1, ua, ub);
    float s2 = rowdot(a2, b2, ua, ub);
    float s3 = rowdot(a3, b3, ua, ub);
#pragma unroll
    for (int off = 32; off > 0; off >>= 1) {  // 4 butterflies interleaved
      s0 += __shfl_xor(s0, off);
      s1 += __shfl_xor(s1, off);
      s2 += __shfl_xor(s2, off);
      s3 += __shfl_xor(s3, off);
    }
    float w0 = __expf(s0), w1 = __expf(s1), w2 = __expf(s2), w3 = __expf(s3);
    l += (w0 + w1) + (w2 + w3);
    accA += a0 * w0; accB += b0 * w0;
    accA += a1 * w1; accB += b1 * w1;
    accA += a2 * w2; accB += b2 * w2;
    accA += a3 * w3; accB += b3 * w3;
  }
  for (; i < cnt; i += WAVES) {   // tail rows
    int r = __shfl(myl, i);
    const f32x4* xp = xb + r * (D / 4);
    f32x4 a = xp[lane];
    f32x4 bb = xp[64 + lane];
    float s = rowdot(a, bb, ua, ub);
#pragma unroll
    for (int off = 32; off > 0; off >>= 1) s += __shfl_xor(s, off);
    float wg = __expf(s);
    l += wg;
    accA += a * wg;
    accB += bb * wg;
  }

  // ---- cross-wave reduce + record ----
  __shared__ float pbuf[WAVES][D];
  __shared__ float s_l[WAVES];
  if (lane == 0) s_l[w] = l;
  *(f32x4*)&pbuf[w][4 * lane] = accA;
  *(f32x4*)&pbuf[w][256 + 4 * lane] = accB;
  __syncthreads();

  int rid = b * CHUNKS + chunk;
  if (t == 0) lsum[rid] = s_l[0] + s_l[1] + s_l[2] + s_l[3];
#pragma unroll
  for (int col = t; col < D; col += MAIN_THREADS) {
    float sum = 0.f;
#pragma unroll
    for (int i2 = 0; i2 < WAVES; ++i2) sum += pbuf[i2][col];
    psum[(size_t)rid * D + col] = sum;
  }
}

// ---------- combine chunk partials per batch (float4-vectorized) ----------
__global__ __launch_bounds__(128) void k_combine(const float* __restrict__ lsum,
                                                 const float* __restrict__ psum,
                                                 float* __restrict__ out) {
  int b = blockIdx.x;          // 16
  int t = threadIdx.x;         // 128 threads x 4 cols = 512
  __shared__ float sl[CHUNKS];
  if (t < CHUNKS) sl[t] = lsum[b * CHUNKS + t];
  __syncthreads();
  float ltot = 0.f;
#pragma unroll
  for (int i = 0; i < CHUNKS; ++i) ltot += sl[i];
  f32x4 o = {0.f, 0.f, 0.f, 0.f};
#pragma unroll 8
  for (int i = 0; i < CHUNKS; ++i)
    o += *(const f32x4*)&psum[(size_t)(b * CHUNKS + i) * D + t * 4];
  float inv = 1.0f / ltot;
  *(f32x4*)&out[b * D + t * 4] = o * inv;
}

extern "C" void kernel_launch(void* const* d_in, const int* in_sizes, int n_in,
                              void* d_out, int out_size, void* d_ws, size_t ws_size,
                              hipStream_t stream) {
  const float* x    = (const float*)d_in[0];
  const int*   mask = (const int*)d_in[1];
  const float* W    = (const float*)d_in[2];
  const float* v    = (const float*)d_in[4];
  float* out = (float*)d_out;
  float* ws  = (float*)d_ws;

  float* u    = ws + WS_U;
  float* lsum = ws + WS_L;
  float* psum = ws + WS_P;

  k_u<<<32, 256, 0, stream>>>(W, v, u);
  dim3 g(CHUNKS, BATCH);
  k_main<<<g, MAIN_THREADS, 0, stream>>>(x, mask, u, lsum, psum);
  k_combine<<<BATCH, 128, 0, stream>>>(lsum, psum, out);
}

// Round 11
// 25.095 us; speedup vs baseline: 1.4967x; 1.1069x over previous
//
#include <hip/hip_runtime.h>
#include <math.h>

#define D 512
#define NROWS 4096
#define BATCH 16
#define CHUNKS 32           // chunks per batch
#define ROWS_PER_CHUNK 128  // NROWS / CHUNKS
#define MAIN_THREADS 512    // 8 waves
#define WAVES 8

// workspace layout (in floats)
#define WS_U    0                      // 512
#define WS_L    512                    // BATCH*CHUNKS = 512 partial denominators
#define WS_P    (WS_L + BATCH*CHUNKS)  // BATCH*CHUNKS*D partial numerators

typedef float f32x4 __attribute__((ext_vector_type(4)));

__device__ __forceinline__ float rowdot(f32x4 a, f32x4 b, f32x4 ua, f32x4 ub) {
  return a.x * ua.x + a.y * ua.y + a.z * ua.z + a.w * ua.w
       + b.x * ub.x + b.y * ub.y + b.z * ub.z + b.w * ub.w;
}

// ---------- u[d] = sum_e v[e]*W[e,d]  (c = b.v cancels in softmax; dropped) ----------
__global__ __launch_bounds__(256) void k_u(const float* __restrict__ W,
                                           const float* __restrict__ v,
                                           float* __restrict__ u) {
  int j = blockIdx.x;             // 32 blocks, 16 cols each
  int t = threadIdx.x;            // 256
  int col = t & 15, rc = t >> 4;  // 16 row-chunks of 32 rows
  int d = j * 16 + col;
  float s = 0.f;
#pragma unroll 8
  for (int i = 0; i < 32; ++i) {
    int e = rc * 32 + i;
    s = fmaf(v[e], W[e * D + d], s);
  }
  __shared__ float red[16][17];
  red[rc][col] = s;
  __syncthreads();
  if (rc == 0) {
    float tot = 0.f;
#pragma unroll
    for (int i = 0; i < 16; ++i) tot += red[i][col];
    u[d] = tot;
  }
}

// ---------- main: compaction + chain-free exp(s)-weighted accumulation ----------
// 512 blocks x 8 waves: same 16 waves/CU residency as the 26.7us config, but
// half the blocks -> per-block overheads (compaction, reduce, psum write,
// dispatch) amortize over 2x rows and psum traffic halves.
__global__ __launch_bounds__(MAIN_THREADS) void k_main(
    const float* __restrict__ x, const int* __restrict__ mask,
    const float* __restrict__ u,
    float* __restrict__ lsum, float* __restrict__ psum) {
  int chunk = blockIdx.x, b = blockIdx.y;
  int t = threadIdx.x;
  int lane = t & 63, w = t >> 6;

  const f32x4* u4 = (const f32x4*)u;
  f32x4 ua = u4[lane];        // d = 4*lane .. 4*lane+3
  f32x4 ub = u4[64 + lane];   // d = 256+4*lane ..

  int base = b * NROWS + chunk * ROWS_PER_CHUNK;

  // ---- compaction: 128-row valid list via two-wave ballot ----
  __shared__ int s_list[ROWS_PER_CHUNK];
  __shared__ int s_wcnt[2];
  __shared__ int s_cnt;
  int mv = 0, pos = 0;
  if (t < 128) {
    mv = mask[base + t];                        // one coalesced 512B load
    unsigned long long bal = __ballot(mv == 1);
    pos = __popcll(bal & ((1ull << lane) - 1ull));
    if (lane == 0) s_wcnt[w] = (int)__popcll(bal);
  }
  __syncthreads();
  if (t < 128) {
    if (mv == 1) s_list[(w ? s_wcnt[0] : 0) + pos] = t;
    if (t == 0) s_cnt = s_wcnt[0] + s_wcnt[1];
  }
  __syncthreads();
  int cnt = s_cnt;

  const f32x4* xb = (const f32x4*)x + (size_t)base * (D / 4);

  float l = 0.f;
  f32x4 accA = {0.f, 0.f, 0.f, 0.f}, accB = {0.f, 0.f, 0.f, 0.f};
#pragma unroll 4
  for (int i = w; i < cnt; i += WAVES) {
    int r = s_list[i];        // uniform LDS broadcast read
    const f32x4* xp = xb + r * (D / 4);
    f32x4 a = xp[lane];
    f32x4 bb = xp[64 + lane];
    float s = rowdot(a, bb, ua, ub);
#pragma unroll
    for (int off = 32; off > 0; off >>= 1) s += __shfl_xor(s, off);
    float wg = __expf(s);
    l += wg;
    accA += a * wg;
    accB += bb * wg;
  }

  // ---- cross-wave reduce + record ----
  __shared__ float pbuf[WAVES][D];
  __shared__ float s_l[WAVES];
  if (lane == 0) s_l[w] = l;
  *(f32x4*)&pbuf[w][4 * lane] = accA;
  *(f32x4*)&pbuf[w][256 + 4 * lane] = accB;
  __syncthreads();

  int rid = b * CHUNKS + chunk;
  if (t == 0) {
    float lt = 0.f;
#pragma unroll
    for (int i = 0; i < WAVES; ++i) lt += s_l[i];
    lsum[rid] = lt;
  }
  {
    int col = t;              // 512 threads, 1 col each
    float sum = 0.f;
#pragma unroll
    for (int i = 0; i < WAVES; ++i) sum += pbuf[i][col];
    psum[(size_t)rid * D + col] = sum;
  }
}

// ---------- combine chunk partials per batch (float4-vectorized) ----------
__global__ __launch_bounds__(128) void k_combine(const float* __restrict__ lsum,
                                                 const float* __restrict__ psum,
                                                 float* __restrict__ out) {
  int b = blockIdx.x;          // 16
  int t = threadIdx.x;         // 128 threads x 4 cols = 512
  __shared__ float sl[CHUNKS];
  if (t < CHUNKS) sl[t] = lsum[b * CHUNKS + t];
  __syncthreads();
  float ltot = 0.f;
#pragma unroll
  for (int i = 0; i < CHUNKS; ++i) ltot += sl[i];
  f32x4 o = {0.f, 0.f, 0.f, 0.f};
#pragma unroll 8
  for (int i = 0; i < CHUNKS; ++i)
    o += *(const f32x4*)&psum[(size_t)(b * CHUNKS + i) * D + t * 4];
  float inv = 1.0f / ltot;
  *(f32x4*)&out[b * D + t * 4] = o * inv;
}

extern "C" void kernel_launch(void* const* d_in, const int* in_sizes, int n_in,
                              void* d_out, int out_size, void* d_ws, size_t ws_size,
                              hipStream_t stream) {
  const float* x    = (const float*)d_in[0];
  const int*   mask = (const int*)d_in[1];
  const float* W    = (const float*)d_in[2];
  const float* v    = (const float*)d_in[4];
  float* out = (float*)d_out;
  float* ws  = (float*)d_ws;

  float* u    = ws + WS_U;
  float* lsum = ws + WS_L;
  float* psum = ws + WS_P;

  k_u<<<32, 256, 0, stream>>>(W, v, u);
  dim3 g(CHUNKS, BATCH);
  k_main<<<g, MAIN_THREADS, 0, stream>>>(x, mask, u, lsum, psum);
  k_combine<<<BATCH, 128, 0, stream>>>(lsum, psum, out);
}

// Round 12
// 23.840 us; speedup vs baseline: 1.5755x; 1.0526x over previous
//
#include <hip/hip_runtime.h>
#include <math.h>

#define D 512
#define NROWS 4096
#define BATCH 16
#define CHUNKS 16           // chunks per batch
#define ROWS_PER_CHUNK 256  // NROWS / CHUNKS
#define MAIN_THREADS 1024   // 16 waves
#define WAVES 16

// workspace layout (in floats)
#define WS_U    0                      // 512
#define WS_L    512                    // BATCH*CHUNKS = 256 partial denominators
#define WS_P    (WS_L + BATCH*CHUNKS)  // BATCH*CHUNKS*D partial numerators

typedef float f32x4 __attribute__((ext_vector_type(4)));

__device__ __forceinline__ float rowdot(f32x4 a, f32x4 b, f32x4 ua, f32x4 ub) {
  return a.x * ua.x + a.y * ua.y + a.z * ua.z + a.w * ua.w
       + b.x * ub.x + b.y * ub.y + b.z * ub.z + b.w * ub.w;
}

// ---------- u[d] = sum_e v[e]*W[e,d]  (c = b.v cancels in softmax; dropped) ----------
__global__ __launch_bounds__(256) void k_u(const float* __restrict__ W,
                                           const float* __restrict__ v,
                                           float* __restrict__ u) {
  int j = blockIdx.x;             // 32 blocks, 16 cols each
  int t = threadIdx.x;            // 256
  int col = t & 15, rc = t >> 4;  // 16 row-chunks of 32 rows
  int d = j * 16 + col;
  float s = 0.f;
#pragma unroll 8
  for (int i = 0; i < 32; ++i) {
    int e = rc * 32 + i;
    s = fmaf(v[e], W[e * D + d], s);
  }
  __shared__ float red[16][17];
  red[rc][col] = s;
  __syncthreads();
  if (rc == 0) {
    float tot = 0.f;
#pragma unroll
    for (int i = 0; i < 16; ++i) tot += red[i][col];
    u[d] = tot;
  }
}

// ---------- main: compaction + chain-free exp(s)-weighted accumulation ----------
// 256 blocks x 16 waves = exactly 1 block/CU, 16 waves/CU (same residency as
// the 25.1us config) -- per-block overheads amortize over 2x rows, psum
// traffic halves, zero launch tail.
__global__ __launch_bounds__(MAIN_THREADS) void k_main(
    const float* __restrict__ x, const int* __restrict__ mask,
    const float* __restrict__ u,
    float* __restrict__ lsum, float* __restrict__ psum) {
  int chunk = blockIdx.x, b = blockIdx.y;
  int t = threadIdx.x;
  int lane = t & 63, w = t >> 6;

  const f32x4* u4 = (const f32x4*)u;
  f32x4 ua = u4[lane];        // d = 4*lane .. 4*lane+3
  f32x4 ub = u4[64 + lane];   // d = 256+4*lane ..

  int base = b * NROWS + chunk * ROWS_PER_CHUNK;

  // ---- compaction: 256-row valid list via 4-wave ballot ----
  __shared__ int s_list[ROWS_PER_CHUNK];
  __shared__ int s_wcnt[4];
  __shared__ int s_cnt;
  int mv = 0, pos = 0;
  if (t < 256) {
    mv = mask[base + t];                        // one coalesced 1KB load
    unsigned long long bal = __ballot(mv == 1);
    pos = __popcll(bal & ((1ull << lane) - 1ull));
    if (lane == 0) s_wcnt[w] = (int)__popcll(bal);
  }
  __syncthreads();
  if (t < 256) {
    int off = 0;
#pragma unroll
    for (int k = 0; k < 4; ++k) off += (k < w) ? s_wcnt[k] : 0;
    if (mv == 1) s_list[off + pos] = t;
    if (t == 0) s_cnt = s_wcnt[0] + s_wcnt[1] + s_wcnt[2] + s_wcnt[3];
  }
  __syncthreads();
  int cnt = s_cnt;

  const f32x4* xb = (const f32x4*)x + (size_t)base * (D / 4);

  float l = 0.f;
  f32x4 accA = {0.f, 0.f, 0.f, 0.f}, accB = {0.f, 0.f, 0.f, 0.f};
#pragma unroll 4
  for (int i = w; i < cnt; i += WAVES) {
    int r = s_list[i];        // uniform LDS broadcast read
    const f32x4* xp = xb + r * (D / 4);
    f32x4 a = xp[lane];
    f32x4 bb = xp[64 + lane];
    float s = rowdot(a, bb, ua, ub);
#pragma unroll
    for (int off = 32; off > 0; off >>= 1) s += __shfl_xor(s, off);
    float wg = __expf(s);
    l += wg;
    accA += a * wg;
    accB += bb * wg;
  }

  // ---- cross-wave reduce + record ----
  __shared__ float pbuf[WAVES][D];
  __shared__ float s_l[WAVES];
  if (lane == 0) s_l[w] = l;
  *(f32x4*)&pbuf[w][4 * lane] = accA;
  *(f32x4*)&pbuf[w][256 + 4 * lane] = accB;
  __syncthreads();

  int rid = b * CHUNKS + chunk;
  if (t == 0) {
    float lt = 0.f;
#pragma unroll
    for (int i = 0; i < WAVES; ++i) lt += s_l[i];
    lsum[rid] = lt;
  }
  if (t < D) {                // 512 of 1024 threads, 1 col each
    float sum = 0.f;
#pragma unroll
    for (int i = 0; i < WAVES; ++i) sum += pbuf[i][t];
    psum[(size_t)rid * D + t] = sum;
  }
}

// ---------- combine chunk partials per batch (float4-vectorized) ----------
__global__ __launch_bounds__(128) void k_combine(const float* __restrict__ lsum,
                                                 const float* __restrict__ psum,
                                                 float* __restrict__ out) {
  int b = blockIdx.x;          // 16
  int t = threadIdx.x;         // 128 threads x 4 cols = 512
  __shared__ float sl[CHUNKS];
  if (t < CHUNKS) sl[t] = lsum[b * CHUNKS + t];
  __syncthreads();
  float ltot = 0.f;
#pragma unroll
  for (int i = 0; i < CHUNKS; ++i) ltot += sl[i];
  f32x4 o = {0.f, 0.f, 0.f, 0.f};
#pragma unroll
  for (int i = 0; i < CHUNKS; ++i)
    o += *(const f32x4*)&psum[(size_t)(b * CHUNKS + i) * D + t * 4];
  float inv = 1.0f / ltot;
  *(f32x4*)&out[b * D + t * 4] = o * inv;
}

extern "C" void kernel_launch(void* const* d_in, const int* in_sizes, int n_in,
                              void* d_out, int out_size, void* d_ws, size_t ws_size,
                              hipStream_t stream) {
  const float* x    = (const float*)d_in[0];
  const int*   mask = (const int*)d_in[1];
  const float* W    = (const float*)d_in[2];
  const float* v    = (const float*)d_in[4];
  float* out = (float*)d_out;
  float* ws  = (float*)d_ws;

  float* u    = ws + WS_U;
  float* lsum = ws + WS_L;
  float* psum = ws + WS_P;

  k_u<<<32, 256, 0, stream>>>(W, v, u);
  dim3 g(CHUNKS, BATCH);
  k_main<<<g, MAIN_THREADS, 0, stream>>>(x, mask, u, lsum, psum);
  k_combine<<<BATCH, 128, 0, stream>>>(lsum, psum, out);
}